// Round 1
// baseline (197.282 us; speedup 1.0000x reference)
//
#include <hip/hip_runtime.h>

namespace {
constexpr int B = 16, C = 128, H = 64, W = 64;
constexpr int HEADS = 4, HD = 32;
constexpr float SCALE = 0.17677669529663687f; // 32^-0.5

__global__ __launch_bounds__(256, 2) void dilate_attn(
    const float* __restrict__ q, const float* __restrict__ k,
    const float* __restrict__ v, float* __restrict__ out) {
  const int tid  = threadIdx.x;
  const int wp   = tid & 31;          // w-pair index: pixels 2*wp, 2*wp+1
  const int head = (tid >> 5) & 3;
  const int rsub = tid >> 7;          // 2 rows per block

  // XCD-band mapping: blockIdx % 8 -> XCD (round-robin heuristic).
  // Each XCD owns 2 full images (b = xcd*2 + slot/32) -> halo reuse stays in one L2.
  const int i    = blockIdx.x;
  const int xcd  = i & 7;
  const int slot = i >> 3;            // 0..63
  const int b    = xcd * 2 + (slot >> 5);
  const int h    = ((slot & 31) << 1) | rsub;
  const int w0   = wp << 1;

  const size_t plane = (size_t)H * W;                    // 4096
  const size_t cbase = ((size_t)b * C + head * HD) * plane;
  const float* qp = q + cbase + (size_t)h * W + w0;
  const float* kp = k + cbase;
  const float* vp = v + cbase;

  // 9 dilated neighbor offsets; OOB -> clamped addr + mask (branchless inner loops)
  int   offs[9];
  float mask[9];
  #pragma unroll
  for (int iy = 0; iy < 3; ++iy) {
    #pragma unroll
    for (int jx = 0; jx < 3; ++jx) {
      const int kk = iy * 3 + jx;
      const int hh = h + 2 * (iy - 1);
      const int ww = w0 + 2 * (jx - 1);    // even: float2 at (hh,ww) covers both pixels
      const bool ok = ((unsigned)hh < (unsigned)H) && ((unsigned)ww < (unsigned)(W - 1));
      offs[kk] = ok ? hh * W + ww : 0;
      mask[kk] = ok ? 1.0f : 0.0f;
    }
  }

  // ---- Phase 1: logits (QK^T), 2 pixels x 9 keys ----
  float l0[9], l1[9];
  #pragma unroll
  for (int kk = 0; kk < 9; ++kk) { l0[kk] = 0.0f; l1[kk] = 0.0f; }

  #pragma unroll
  for (int d = 0; d < HD; ++d) {
    const float2 qv = *(const float2*)(qp + d * plane);
    const float* kc = kp + d * plane;
    #pragma unroll
    for (int kk = 0; kk < 9; ++kk) {
      const float2 kv = *(const float2*)(kc + offs[kk]);
      l0[kk] = fmaf(qv.x, kv.x, l0[kk]);
      l1[kk] = fmaf(qv.y, kv.y, l1[kk]);
    }
  }

  // zero-padded keys: logit exactly 0, still in the softmax denominator
  float m0 = -1e30f, m1 = -1e30f;
  #pragma unroll
  for (int kk = 0; kk < 9; ++kk) {
    l0[kk] *= mask[kk];
    l1[kk] *= mask[kk];
    m0 = fmaxf(m0, l0[kk]);
    m1 = fmaxf(m1, l1[kk]);
  }

  // ---- Phase 2: softmax over 9 ----
  float p0[9], p1[9];
  float s0 = 0.0f, s1 = 0.0f;
  #pragma unroll
  for (int kk = 0; kk < 9; ++kk) {
    p0[kk] = __expf((l0[kk] - m0) * SCALE);
    p1[kk] = __expf((l1[kk] - m1) * SCALE);
    s0 += p0[kk];
    s1 += p1[kk];
  }
  const float r0 = 1.0f / s0, r1 = 1.0f / s1;
  #pragma unroll
  for (int kk = 0; kk < 9; ++kk) {
    p0[kk] *= r0 * mask[kk];   // fold V zero-padding into the weight
    p1[kk] *= r1 * mask[kk];
  }

  // ---- Phase 3: PV, blocked 4 channels at a time; float4 stores ----
  float* op0 = out + (((size_t)b * H + h) * W + w0) * C + head * HD;
  float* op1 = op0 + C;

  #pragma unroll
  for (int dg = 0; dg < 8; ++dg) {
    float o0[4] = {0, 0, 0, 0}, o1[4] = {0, 0, 0, 0};
    #pragma unroll
    for (int di = 0; di < 4; ++di) {
      const float* vc = vp + (dg * 4 + di) * plane;
      #pragma unroll
      for (int kk = 0; kk < 9; ++kk) {
        const float2 vv = *(const float2*)(vc + offs[kk]);
        o0[di] = fmaf(p0[kk], vv.x, o0[di]);
        o1[di] = fmaf(p1[kk], vv.y, o1[di]);
      }
    }
    *(float4*)(op0 + dg * 4) = make_float4(o0[0], o0[1], o0[2], o0[3]);
    *(float4*)(op1 + dg * 4) = make_float4(o1[0], o1[1], o1[2], o1[3]);
  }
}
} // namespace

extern "C" void kernel_launch(void* const* d_in, const int* in_sizes, int n_in,
                              void* d_out, int out_size, void* d_ws, size_t ws_size,
                              hipStream_t stream) {
  const float* q = (const float*)d_in[0];
  const float* k = (const float*)d_in[1];
  const float* v = (const float*)d_in[2];
  float* o = (float*)d_out;
  // grid: 8 XCD bands x 64 slots (2 images x 32 row-pairs per XCD)
  dilate_attn<<<dim3(512), dim3(256), 0, stream>>>(q, k, v, o);
}

// Round 2
// 161.352 us; speedup vs baseline: 1.2227x; 1.2227x over previous
//
#include <hip/hip_runtime.h>

namespace {
constexpr int B = 16, C = 128, H = 64, W = 64;
constexpr int HEADS = 4, HD = 32;
constexpr float SCALE = 0.17677669529663687f; // 32^-0.5

// Block = one image row (64 px) x 4 heads; thread = one (pixel, head).
// lane = w -> every global access is lane-contiguous (coalesced).
__global__ __launch_bounds__(256, 4) void dilate_attn(
    const float* __restrict__ q, const float* __restrict__ k,
    const float* __restrict__ v, float* __restrict__ out) {
  __shared__ float4 smem[64 * 32];  // 64 px x 32 float4 (=128 ch) = 32 KB

  const int tid  = threadIdx.x;
  const int w    = tid & 63;
  const int head = tid >> 6;        // wave index = head

  // XCD swizzle: blockIdx%8 -> XCD (round-robin heuristic). Each XCD owns a
  // contiguous slot range -> rolling 5-row k/v halo window stays in its L2.
  const int blk  = blockIdx.x;
  const int slot = ((blk & 7) << 7) | (blk >> 3);  // bijective 0..1023
  const int b    = slot >> 6;
  const int h    = slot & 63;

  const size_t plane = (size_t)H * W;  // 4096
  const size_t cbase = ((size_t)b * C + head * HD) * plane;
  const float* qp = q + cbase + (size_t)h * W + w;
  const float* kp = k + cbase;
  const float* vp = v + cbase;

  // 9 dilated taps; OOB -> clamped offset + zero mask (branchless)
  int   offs[9];
  float mask[9];
  #pragma unroll
  for (int iy = 0; iy < 3; ++iy) {
    #pragma unroll
    for (int jx = 0; jx < 3; ++jx) {
      const int kk = iy * 3 + jx;
      const int hh = h + 2 * (iy - 1);
      const int ww = w + 2 * (jx - 1);
      const bool ok = ((unsigned)hh < (unsigned)H) && ((unsigned)ww < (unsigned)W);
      offs[kk] = ok ? hh * W + ww : 0;
      mask[kk] = ok ? 1.0f : 0.0f;
    }
  }

  // ---- Phase 1: logits, batched 4 channels (36 loads in flight) ----
  float l[9];
  #pragma unroll
  for (int kk = 0; kk < 9; ++kk) l[kk] = 0.0f;

  #pragma unroll
  for (int dg = 0; dg < 8; ++dg) {
    float qd[4], kd[4][9];
    #pragma unroll
    for (int di = 0; di < 4; ++di) {
      const int d = dg * 4 + di;
      qd[di] = qp[d * plane];
      const float* kc = kp + d * plane;
      #pragma unroll
      for (int kk = 0; kk < 9; ++kk) kd[di][kk] = kc[offs[kk]];
    }
    #pragma unroll
    for (int di = 0; di < 4; ++di)
      #pragma unroll
      for (int kk = 0; kk < 9; ++kk) l[kk] = fmaf(qd[di], kd[di][kk], l[kk]);
  }

  // ---- Phase 2: softmax over 9 (zero-padded keys keep logit 0 in denom) ----
  float m = -1e30f;
  #pragma unroll
  for (int kk = 0; kk < 9; ++kk) {
    l[kk] *= mask[kk];
    m = fmaxf(m, l[kk]);
  }
  float p[9], s = 0.0f;
  #pragma unroll
  for (int kk = 0; kk < 9; ++kk) {
    p[kk] = __expf((l[kk] - m) * SCALE);
    s += p[kk];
  }
  const float r = 1.0f / s;
  #pragma unroll
  for (int kk = 0; kk < 9; ++kk) p[kk] *= r * mask[kk];  // fold V zero-pad

  // ---- Phase 3: PV, batched 4 channels; results staged in LDS (XOR swizzle) ----
  #pragma unroll
  for (int dg = 0; dg < 8; ++dg) {
    float vd[4][9];
    #pragma unroll
    for (int di = 0; di < 4; ++di) {
      const float* vc = vp + (dg * 4 + di) * plane;
      #pragma unroll
      for (int kk = 0; kk < 9; ++kk) vd[di][kk] = vc[offs[kk]];
    }
    float o[4] = {0, 0, 0, 0};
    #pragma unroll
    for (int di = 0; di < 4; ++di)
      #pragma unroll
      for (int kk = 0; kk < 9; ++kk) o[di] = fmaf(p[kk], vd[di][kk], o[di]);

    const int c4 = head * 8 + dg;                       // float4-chunk index 0..31
    smem[(w << 5) | (c4 ^ (w & 31))] = make_float4(o[0], o[1], o[2], o[3]);
  }

  __syncthreads();

  // ---- Coalesced store: 1 KB contiguous per wave per instruction ----
  float4* outp = (float4*)(out + ((size_t)(b * H + h) * W) * C);  // 64 px x 128 ch
  #pragma unroll
  for (int it = 0; it < 8; ++it) {
    const int L = it * 256 + tid;
    const int px = L >> 5, c = L & 31;
    outp[L] = smem[(px << 5) | (c ^ (px & 31))];
  }
}
} // namespace

extern "C" void kernel_launch(void* const* d_in, const int* in_sizes, int n_in,
                              void* d_out, int out_size, void* d_ws, size_t ws_size,
                              hipStream_t stream) {
  const float* q = (const float*)d_in[0];
  const float* k = (const float*)d_in[1];
  const float* v = (const float*)d_in[2];
  float* o = (float*)d_out;
  dilate_attn<<<dim3(1024), dim3(256), 0, stream>>>(q, k, v, o);
}